// Round 1
// baseline (442.516 us; speedup 1.0000x reference)
//
#include <hip/hip_runtime.h>
#include <hip/hip_bf16.h>
#include <cfloat>

#define N_NODES 8192
#define F_IN    128
#define F_OUT   64
#define HEADS   2
#define LEAKY   0.2f
#define ROWS    8      // rows of X per block in feats kernel
#define CAP     2048   // max neighbors per row held in LDS (mean ~33, binomial p=0.004)

// Kernel 1: feats[h][n][o] = sum_f X[n][f] * W[h][f][o]
// fused epilogue: a_s[h][n] = <feats[h][n][:], attn_self[h][:]>, same for a_n.
// Block = 128 threads = 2 waves; wave h owns head h, lane = output dim o.
__global__ __launch_bounds__(128) void feats_kernel(
    const float* __restrict__ X, const float* __restrict__ W,
    const float* __restrict__ attn_self, const float* __restrict__ attn_neigh,
    float* __restrict__ feats, float* __restrict__ a_s, float* __restrict__ a_n)
{
    __shared__ float Xs[ROWS][F_IN];   // 4 KB
    const int tid = threadIdx.x;
    const int n0  = blockIdx.x * ROWS;

    for (int k = tid; k < ROWS * F_IN; k += 128) {
        Xs[k / F_IN][k % F_IN] = X[(size_t)(n0 + k / F_IN) * F_IN + (k % F_IN)];
    }
    __syncthreads();

    const int h = tid >> 6;
    const int o = tid & 63;
    const float* Wh = W + (size_t)h * F_IN * F_OUT;

    float acc[ROWS];
    #pragma unroll
    for (int r = 0; r < ROWS; ++r) acc[r] = 0.f;

    for (int f = 0; f < F_IN; ++f) {
        float wv = Wh[f * F_OUT + o];      // coalesced 256B/wave, L1/L2-resident
        #pragma unroll
        for (int r = 0; r < ROWS; ++r) acc[r] += Xs[r][f] * wv;  // Xs broadcast
    }

    const float asv = attn_self[h * F_OUT + o];
    const float anv = attn_neigh[h * F_OUT + o];
    #pragma unroll
    for (int r = 0; r < ROWS; ++r) {
        const int n = n0 + r;
        const float v = acc[r];
        feats[((size_t)h * N_NODES + n) * F_OUT + o] = v;
        float s = v * asv;
        float t = v * anv;
        #pragma unroll
        for (int off = 32; off > 0; off >>= 1) {   // wave-64 reduce
            s += __shfl_down(s, off);
            t += __shfl_down(t, off);
        }
        if (o == 0) {
            a_s[h * N_NODES + n] = s;
            a_n[h * N_NODES + n] = t;
        }
    }
}

// Kernel 2: one block per destination row i.
// Phase 1: scan A[i,:] (float4), compact nonzero column indices into LDS.
// Phase 2: e_hj = leakyrelu(a_s[h][i] + a_n[h][j]); block softmax (max, exp, sum).
// Phase 3: 128 threads (h,o): acc = sum_j w_hj * feats[h][j][o]; head-mean + ReLU.
__global__ __launch_bounds__(256) void gat_row_kernel(
    const float* __restrict__ A, const float* __restrict__ feats,
    const float* __restrict__ a_s, const float* __restrict__ a_n,
    const float* __restrict__ biases, float* __restrict__ out)
{
    __shared__ int   nbr[CAP];     // 8 KB
    __shared__ float w0[CAP];      // 8 KB — head 0 logits -> weights
    __shared__ float w1[CAP];      // 8 KB — head 1
    __shared__ int   cnt;
    __shared__ float red0[4], red1[4];
    __shared__ float m0s, m1s, l0s, l1s;
    __shared__ float accs[128];

    const int tid = threadIdx.x;
    const int i   = blockIdx.x;
    if (tid == 0) cnt = 0;
    __syncthreads();

    // ---- Phase 1: sparse compaction of A row i (the 256 MiB HBM scan) ----
    const float4* Arow = (const float4*)(A + (size_t)i * N_NODES);
    for (int c = tid; c < N_NODES / 4; c += 256) {
        float4 v = Arow[c];
        if (v.x > 0.5f) { int p = atomicAdd(&cnt, 1); if (p < CAP) nbr[p] = 4*c + 0; }
        if (v.y > 0.5f) { int p = atomicAdd(&cnt, 1); if (p < CAP) nbr[p] = 4*c + 1; }
        if (v.z > 0.5f) { int p = atomicAdd(&cnt, 1); if (p < CAP) nbr[p] = 4*c + 2; }
        if (v.w > 0.5f) { int p = atomicAdd(&cnt, 1); if (p < CAP) nbr[p] = 4*c + 3; }
    }
    __syncthreads();
    const int count = min(cnt, CAP);   // self-loop guarantees count >= 1

    // ---- Phase 2a: logits ----
    const float as0 = a_s[i];
    const float as1 = a_s[N_NODES + i];
    for (int k = tid; k < count; k += 256) {
        const int j = nbr[k];
        float e0 = as0 + a_n[j];            e0 = e0 > 0.f ? e0 : LEAKY * e0;
        float e1 = as1 + a_n[N_NODES + j];  e1 = e1 > 0.f ? e1 : LEAKY * e1;
        w0[k] = e0;
        w1[k] = e1;
    }
    __syncthreads();

    // ---- Phase 2b: row max ----
    float m0 = -FLT_MAX, m1 = -FLT_MAX;
    for (int k = tid; k < count; k += 256) {
        m0 = fmaxf(m0, w0[k]);
        m1 = fmaxf(m1, w1[k]);
    }
    #pragma unroll
    for (int off = 32; off > 0; off >>= 1) {
        m0 = fmaxf(m0, __shfl_down(m0, off));
        m1 = fmaxf(m1, __shfl_down(m1, off));
    }
    if ((tid & 63) == 0) { red0[tid >> 6] = m0; red1[tid >> 6] = m1; }
    __syncthreads();
    if (tid == 0) {
        m0s = fmaxf(fmaxf(red0[0], red0[1]), fmaxf(red0[2], red0[3]));
        m1s = fmaxf(fmaxf(red1[0], red1[1]), fmaxf(red1[2], red1[3]));
    }
    __syncthreads();

    // ---- Phase 2c: exp + denominator ----
    const float m0f = m0s, m1f = m1s;
    float s0 = 0.f, s1 = 0.f;
    for (int k = tid; k < count; k += 256) {
        float x0 = __expf(w0[k] - m0f); w0[k] = x0; s0 += x0;
        float x1 = __expf(w1[k] - m1f); w1[k] = x1; s1 += x1;
    }
    #pragma unroll
    for (int off = 32; off > 0; off >>= 1) {
        s0 += __shfl_down(s0, off);
        s1 += __shfl_down(s1, off);
    }
    if ((tid & 63) == 0) { red0[tid >> 6] = s0; red1[tid >> 6] = s1; }
    __syncthreads();
    if (tid == 0) {
        l0s = red0[0] + red0[1] + red0[2] + red0[3];
        l1s = red1[0] + red1[1] + red1[2] + red1[3];
    }
    __syncthreads();

    // ---- Phase 3: weighted gather-sum of feats ----
    if (tid < 128) {
        const int h = tid >> 6;
        const int o = tid & 63;
        const float* fh = feats + (size_t)h * N_NODES * F_OUT;
        const float* wh = h ? w1 : w0;
        const float inv_l = 1.f / (h ? l1s : l0s);
        float acc = 0.f;
        for (int k = 0; k < count; ++k) {
            // wh[k]/nbr[k]: LDS broadcast; feats row: coalesced 256B gather (L2/L3-hit)
            acc += wh[k] * fh[(size_t)nbr[k] * F_OUT + o];
        }
        accs[tid] = acc * inv_l + biases[h * F_OUT + o];
    }
    __syncthreads();
    if (tid < 64) {
        float v = 0.5f * (accs[tid] + accs[tid + 64]);   // mean over 2 heads
        out[(size_t)i * F_OUT + tid] = v > 0.f ? v : 0.f; // relu
    }
}

extern "C" void kernel_launch(void* const* d_in, const int* in_sizes, int n_in,
                              void* d_out, int out_size, void* d_ws, size_t ws_size,
                              hipStream_t stream) {
    const float* X          = (const float*)d_in[0];  // [8192, 128]
    const float* A          = (const float*)d_in[1];  // [8192, 8192]
    const float* W          = (const float*)d_in[2];  // [2, 128, 64]
    const float* biases     = (const float*)d_in[3];  // [2, 64]
    const float* attn_self  = (const float*)d_in[4];  // [2, 64]
    const float* attn_neigh = (const float*)d_in[5];  // [2, 64]
    float* out = (float*)d_out;                       // [8192, 64]

    float* feats = (float*)d_ws;                              // 2*8192*64 fp32 = 4 MB
    float* a_s   = feats + (size_t)HEADS * N_NODES * F_OUT;   // 2*8192
    float* a_n   = a_s + HEADS * N_NODES;                     // 2*8192

    feats_kernel<<<N_NODES / ROWS, 128, 0, stream>>>(
        X, W, attn_self, attn_neigh, feats, a_s, a_n);
    gat_row_kernel<<<N_NODES, 256, 0, stream>>>(
        A, feats, a_s, a_n, biases, out);
}

// Round 2
// 435.898 us; speedup vs baseline: 1.0152x; 1.0152x over previous
//
#include <hip/hip_runtime.h>
#include <hip/hip_bf16.h>
#include <cfloat>

#define N_NODES 8192
#define F_IN    128
#define F_OUT   64
#define HEADS   2
#define LEAKY   0.2f
#define ROWS    8      // rows of X per block in feats kernel
#define CAP     256    // max neighbors per row (mean ~33, std ~5.7; 256 is ~40 sigma)

// ---------------------------------------------------------------------------
// Kernel 1: feats[h][n][o] = sum_f X[n][f] * W[h][f][o]
// fused epilogue: a_s[h][n] = <feats[h][n][:], attn_self[h][:]>, same for a_n.
// Block = 128 threads = 2 waves; wave h owns head h, lane = output dim o.
// ---------------------------------------------------------------------------
__global__ __launch_bounds__(128) void feats_kernel(
    const float* __restrict__ X, const float* __restrict__ W,
    const float* __restrict__ attn_self, const float* __restrict__ attn_neigh,
    float* __restrict__ feats, float* __restrict__ a_s, float* __restrict__ a_n)
{
    __shared__ float Xs[ROWS][F_IN];   // 4 KB
    const int tid = threadIdx.x;
    const int n0  = blockIdx.x * ROWS;

    for (int k = tid; k < ROWS * F_IN; k += 128) {
        Xs[k / F_IN][k % F_IN] = X[(size_t)(n0 + k / F_IN) * F_IN + (k % F_IN)];
    }
    __syncthreads();

    const int h = tid >> 6;
    const int o = tid & 63;
    const float* Wh = W + (size_t)h * F_IN * F_OUT;

    float acc[ROWS];
    #pragma unroll
    for (int r = 0; r < ROWS; ++r) acc[r] = 0.f;

    for (int f = 0; f < F_IN; ++f) {
        float wv = Wh[f * F_OUT + o];      // coalesced 256B/wave, L1/L2-resident
        #pragma unroll
        for (int r = 0; r < ROWS; ++r) acc[r] += Xs[r][f] * wv;  // Xs broadcast
    }

    const float asv = attn_self[h * F_OUT + o];
    const float anv = attn_neigh[h * F_OUT + o];
    #pragma unroll
    for (int r = 0; r < ROWS; ++r) {
        const int n = n0 + r;
        const float v = acc[r];
        feats[((size_t)h * N_NODES + n) * F_OUT + o] = v;
        float s = v * asv;
        float t = v * anv;
        #pragma unroll
        for (int off = 32; off > 0; off >>= 1) {   // wave-64 reduce
            s += __shfl_down(s, off);
            t += __shfl_down(t, off);
        }
        if (o == 0) {
            a_s[h * N_NODES + n] = s;
            a_n[h * N_NODES + n] = t;
        }
    }
}

// ---------------------------------------------------------------------------
// Kernel 2: streaming sparse compaction of A (268 MB scan at HBM BW).
// Grid-stride over float4; per wave, 64 consecutive float4 = 256 floats,
// always within one row (row = 2048 float4, 64-aligned) -> row is
// wave-uniform. Ballot compaction: 4 ballots + 1 leader atomic per chunk.
// ---------------------------------------------------------------------------
__global__ __launch_bounds__(256) void scan_kernel(
    const float* __restrict__ A, int* __restrict__ cnt, int* __restrict__ nbrs)
{
    const int lane = threadIdx.x & 63;
    const size_t total4 = (size_t)N_NODES * N_NODES / 4;   // 16M float4
    const size_t stride = (size_t)gridDim.x * blockDim.x;
    const unsigned long long lt_mask = (lane == 63) ? 0x7FFFFFFFFFFFFFFFULL
                                                    : ((1ULL << lane) - 1ULL);
    for (size_t c = (size_t)blockIdx.x * blockDim.x + threadIdx.x;
         c < total4; c += stride) {
        const float4 v = ((const float4*)A)[c];
        const int row  = (int)(c >> 11);            // 2048 float4 per row
        const int col0 = (int)((c & 2047) << 2);
        #pragma unroll
        for (int comp = 0; comp < 4; ++comp) {
            const float x = (comp == 0) ? v.x : (comp == 1) ? v.y
                          : (comp == 2) ? v.z : v.w;
            const bool nz = (x > 0.5f);
            const unsigned long long mask = __ballot(nz);
            if (mask) {                              // wave-uniform branch
                int base = 0;
                if (lane == 0) base = atomicAdd(&cnt[row], __popcll(mask));
                base = __shfl(base, 0);
                if (nz) {
                    const int pos = base + __popcll(mask & lt_mask);
                    if (pos < CAP)
                        nbrs[(size_t)row * CAP + pos] = col0 + comp;
                }
            }
        }
    }
}

// ---------------------------------------------------------------------------
// Kernel 3: per-row softmax + weighted gather. One block (128 thr) per row.
// Tiny LDS (~3.3 KB) -> 8 blocks/CU resident, gather hits L2/L3 (feats=4MB).
// ---------------------------------------------------------------------------
__global__ __launch_bounds__(128) void row_kernel(
    const int* __restrict__ cnt, const int* __restrict__ nbrs,
    const float* __restrict__ feats, const float* __restrict__ a_s,
    const float* __restrict__ a_n, const float* __restrict__ biases,
    float* __restrict__ out)
{
    __shared__ int   jj[CAP];
    __shared__ float w0[CAP];
    __shared__ float w1[CAP];
    __shared__ float lh[2];
    __shared__ float accs[128];

    const int i   = blockIdx.x;
    const int tid = threadIdx.x;
    const int count = min(cnt[i], CAP);   // self-loop guarantees count >= 1

    // logits for both heads
    const float as0 = a_s[i];
    const float as1 = a_s[N_NODES + i];
    for (int k = tid; k < count; k += 128) {
        const int j = nbrs[(size_t)i * CAP + k];
        jj[k] = j;
        float e0 = as0 + a_n[j];            e0 = e0 > 0.f ? e0 : LEAKY * e0;
        float e1 = as1 + a_n[N_NODES + j];  e1 = e1 > 0.f ? e1 : LEAKY * e1;
        w0[k] = e0;
        w1[k] = e1;
    }
    __syncthreads();

    // wave h reduces head h: max, then exp + sum (in-place into w_h)
    const int h    = tid >> 6;
    const int lane = tid & 63;
    float* wh = h ? w1 : w0;

    float m = -FLT_MAX;
    for (int k = lane; k < count; k += 64) m = fmaxf(m, wh[k]);
    #pragma unroll
    for (int off = 32; off > 0; off >>= 1) m = fmaxf(m, __shfl_down(m, off));
    m = __shfl(m, 0);

    float s = 0.f;
    for (int k = lane; k < count; k += 64) {
        const float p = __expf(wh[k] - m);
        wh[k] = p;
        s += p;
    }
    #pragma unroll
    for (int off = 32; off > 0; off >>= 1) s += __shfl_down(s, off);
    if (lane == 0) lh[h] = s;
    __syncthreads();

    // gather: thread (h, o=lane) accumulates sum_k w_h[k] * feats[h][jj[k]][o]
    const float* fh    = feats + (size_t)h * N_NODES * F_OUT;
    const float  inv_l = 1.f / lh[h];
    float acc = 0.f;
    for (int k = 0; k < count; ++k) {
        acc += wh[k] * fh[(size_t)jj[k] * F_OUT + lane];   // coalesced 256B/wave
    }
    accs[tid] = acc * inv_l + biases[h * F_OUT + lane];
    __syncthreads();

    if (tid < 64) {
        const float v = 0.5f * (accs[tid] + accs[tid + 64]);  // mean over heads
        out[(size_t)i * F_OUT + tid] = v > 0.f ? v : 0.f;     // relu
    }
}

extern "C" void kernel_launch(void* const* d_in, const int* in_sizes, int n_in,
                              void* d_out, int out_size, void* d_ws, size_t ws_size,
                              hipStream_t stream) {
    const float* X          = (const float*)d_in[0];  // [8192, 128]
    const float* A          = (const float*)d_in[1];  // [8192, 8192]
    const float* W          = (const float*)d_in[2];  // [2, 128, 64]
    const float* biases     = (const float*)d_in[3];  // [2, 64]
    const float* attn_self  = (const float*)d_in[4];  // [2, 64]
    const float* attn_neigh = (const float*)d_in[5];  // [2, 64]
    float* out = (float*)d_out;                       // [8192, 64]

    // ws layout (fp32/int32 elements):
    float* feats = (float*)d_ws;                              // 2*8192*64 = 4 MB
    float* a_s   = feats + (size_t)HEADS * N_NODES * F_OUT;   // 16384
    float* a_n   = a_s + HEADS * N_NODES;                     // 16384
    int*   cnt   = (int*)(a_n + HEADS * N_NODES);             // 8192
    int*   nbrs  = cnt + N_NODES;                             // 8192*256 = 8 MB

    hipMemsetAsync(cnt, 0, N_NODES * sizeof(int), stream);

    feats_kernel<<<N_NODES / ROWS, 128, 0, stream>>>(
        X, W, attn_self, attn_neigh, feats, a_s, a_n);
    scan_kernel<<<4096, 256, 0, stream>>>(A, cnt, nbrs);
    row_kernel<<<N_NODES, 128, 0, stream>>>(
        cnt, nbrs, feats, a_s, a_n, biases, out);
}

// Round 3
// 371.084 us; speedup vs baseline: 1.1925x; 1.1747x over previous
//
#include <hip/hip_runtime.h>
#include <hip/hip_bf16.h>
#include <cfloat>

#define N_NODES 8192
#define F_IN    128
#define F_OUT   64
#define HEADS   2
#define LEAKY   0.2f
#define ROWS    8     // rows of X per block in feats kernel
#define CAP     128   // per-row neighbor cap; Binomial(8192,0.004) max over 8192 rows ~60

typedef float f32x4 __attribute__((ext_vector_type(4)));

// ---------------------------------------------------------------------------
// Kernel 1: feats[h][n][o] = sum_f X[n][f] * W[h][f][o]
// fused epilogue: a_s[h][n] = <feats[h][n][:], attn_self[h][:]>, same a_n.
// Block = 128 threads = 2 waves; wave h owns head h, lane = output dim o.
// ---------------------------------------------------------------------------
__global__ __launch_bounds__(128) void feats_kernel(
    const float* __restrict__ X, const float* __restrict__ W,
    const float* __restrict__ attn_self, const float* __restrict__ attn_neigh,
    float* __restrict__ feats, float* __restrict__ a_s, float* __restrict__ a_n)
{
    __shared__ float Xs[ROWS][F_IN];   // 4 KB
    const int tid = threadIdx.x;
    const int n0  = blockIdx.x * ROWS;

    for (int k = tid; k < ROWS * F_IN; k += 128) {
        Xs[k / F_IN][k % F_IN] = X[(size_t)(n0 + k / F_IN) * F_IN + (k % F_IN)];
    }
    __syncthreads();

    const int h = tid >> 6;
    const int o = tid & 63;
    const float* Wh = W + (size_t)h * F_IN * F_OUT;

    float acc[ROWS];
    #pragma unroll
    for (int r = 0; r < ROWS; ++r) acc[r] = 0.f;

    for (int f = 0; f < F_IN; ++f) {
        float wv = Wh[f * F_OUT + o];      // coalesced, L1/L2-resident
        #pragma unroll
        for (int r = 0; r < ROWS; ++r) acc[r] += Xs[r][f] * wv;
    }

    const float asv = attn_self[h * F_OUT + o];
    const float anv = attn_neigh[h * F_OUT + o];
    #pragma unroll
    for (int r = 0; r < ROWS; ++r) {
        const int n = n0 + r;
        const float v = acc[r];
        feats[((size_t)h * N_NODES + n) * F_OUT + o] = v;
        float s = v * asv;
        float t = v * anv;
        #pragma unroll
        for (int off = 32; off > 0; off >>= 1) {
            s += __shfl_down(s, off);
            t += __shfl_down(t, off);
        }
        if (o == 0) {
            a_s[h * N_NODES + n] = s;
            a_n[h * N_NODES + n] = t;
        }
    }
}

// ---------------------------------------------------------------------------
// Kernel 2 (fused): ONE WAVE PER ROW. 8192 waves = 8/SIMD x 1024 SIMDs ->
// fully resident. Per wave: stream A row (32 x 1KB nontemporal float4,
// pipelined), ballot-compact neighbors into private LDS (no atomics),
// two-head softmax via shfl reductions, weighted feats gather, mean+relu.
// No __syncthreads anywhere; all LDS traffic is wave-private.
// ---------------------------------------------------------------------------
__global__ __launch_bounds__(256) void fused_row_kernel(
    const float* __restrict__ A, const float* __restrict__ feats,
    const float* __restrict__ a_s, const float* __restrict__ a_n,
    const float* __restrict__ biases, float* __restrict__ out)
{
    __shared__ int   jj_s[4][CAP];   // 2 KB
    __shared__ float w0_s[4][CAP];   // 2 KB
    __shared__ float w1_s[4][CAP];   // 2 KB

    const int wave = threadIdx.x >> 6;
    const int lane = threadIdx.x & 63;
    const int row  = blockIdx.x * 4 + wave;

    int*   jj = jj_s[wave];
    float* w0 = w0_s[wave];
    float* w1 = w1_s[wave];

    const unsigned long long lt = (1ULL << lane) - 1ULL;   // lanes-below mask

    // ---- Phase 1: stream + compact A row (wave-private, atomic-free) ----
    const f32x4* Arow = (const f32x4*)(A + (size_t)row * N_NODES);  // 2048 f32x4
    int base = 0;                                   // wave-uniform running count
    f32x4 cur = __builtin_nontemporal_load(&Arow[lane]);
    for (int it = 0; it < 32; ++it) {
        f32x4 nxt = cur;
        if (it < 31) nxt = __builtin_nontemporal_load(&Arow[(it + 1) * 64 + lane]);
        const int col0 = (it * 64 + lane) * 4;
        #pragma unroll
        for (int comp = 0; comp < 4; ++comp) {
            const bool nz = cur[comp] > 0.5f;
            const unsigned long long m = __ballot(nz);
            if (nz) {
                const int p = base + __popcll(m & lt);
                if (p < CAP) jj[p] = col0 + comp;
            }
            base += __popcll(m);                    // scalar (uniform) add
        }
        cur = nxt;
    }
    const int count = min(base, CAP);               // self-loop -> count >= 1

    // ---- Phase 2: logits + softmax (both heads), shfl reductions ----
    const float as0 = a_s[row];
    const float as1 = a_s[N_NODES + row];
    float m0 = -FLT_MAX, m1 = -FLT_MAX;
    for (int k = lane; k < count; k += 64) {
        const int j = jj[k];
        float e0 = as0 + a_n[j];            e0 = e0 > 0.f ? e0 : LEAKY * e0;
        float e1 = as1 + a_n[N_NODES + j];  e1 = e1 > 0.f ? e1 : LEAKY * e1;
        w0[k] = e0; w1[k] = e1;
        m0 = fmaxf(m0, e0); m1 = fmaxf(m1, e1);
    }
    #pragma unroll
    for (int off = 32; off > 0; off >>= 1) {
        m0 = fmaxf(m0, __shfl_xor(m0, off));
        m1 = fmaxf(m1, __shfl_xor(m1, off));
    }
    float s0 = 0.f, s1 = 0.f;
    for (int k = lane; k < count; k += 64) {        // lane re-reads its own writes
        const float p0 = __expf(w0[k] - m0); w0[k] = p0; s0 += p0;
        const float p1 = __expf(w1[k] - m1); w1[k] = p1; s1 += p1;
    }
    #pragma unroll
    for (int off = 32; off > 0; off >>= 1) {
        s0 += __shfl_xor(s0, off);
        s1 += __shfl_xor(s1, off);
    }

    // ---- Phase 3: weighted gather of feats (L2-resident, 4 MB table) ----
    const float* f0 = feats;                           // head 0: [N][64]
    const float* f1 = feats + (size_t)N_NODES * F_OUT; // head 1
    float acc0 = 0.f, acc1 = 0.f;
    for (int k = 0; k < count; ++k) {
        const int   j  = jj[k];                        // LDS broadcast
        const float p0 = w0[k];
        const float p1 = w1[k];
        acc0 += p0 * f0[(size_t)j * F_OUT + lane];     // coalesced 256B/wave
        acc1 += p1 * f1[(size_t)j * F_OUT + lane];
    }
    const float v = 0.5f * ((acc0 / s0 + biases[lane]) +
                            (acc1 / s1 + biases[F_OUT + lane]));
    out[(size_t)row * F_OUT + lane] = v > 0.f ? v : 0.f;   // mean + relu
}

extern "C" void kernel_launch(void* const* d_in, const int* in_sizes, int n_in,
                              void* d_out, int out_size, void* d_ws, size_t ws_size,
                              hipStream_t stream) {
    const float* X          = (const float*)d_in[0];  // [8192, 128]
    const float* A          = (const float*)d_in[1];  // [8192, 8192]
    const float* W          = (const float*)d_in[2];  // [2, 128, 64]
    const float* biases     = (const float*)d_in[3];  // [2, 64]
    const float* attn_self  = (const float*)d_in[4];  // [2, 64]
    const float* attn_neigh = (const float*)d_in[5];  // [2, 64]
    float* out = (float*)d_out;                       // [8192, 64]

    float* feats = (float*)d_ws;                              // 2*8192*64 = 4 MB
    float* a_s   = feats + (size_t)HEADS * N_NODES * F_OUT;   // 16384
    float* a_n   = a_s + HEADS * N_NODES;                     // 16384

    feats_kernel<<<N_NODES / ROWS, 128, 0, stream>>>(
        X, W, attn_self, attn_neigh, feats, a_s, a_n);
    fused_row_kernel<<<N_NODES / 4, 256, 0, stream>>>(
        A, feats, a_s, a_n, biases, out);
}

// Round 4
// 371.026 us; speedup vs baseline: 1.1927x; 1.0002x over previous
//
#include <hip/hip_runtime.h>
#include <hip/hip_bf16.h>
#include <cfloat>

#define N_NODES 8192
#define F_IN    128
#define F_OUT   64
#define HEADS   2
#define LEAKY   0.2f
#define ROWS    8     // rows of X per block in feats kernel
#define CAP     128   // per-row neighbor cap; Binomial(8192,0.004) max ~60 incl. self-loop

typedef float f32x4 __attribute__((ext_vector_type(4)));

// ---------------------------------------------------------------------------
// Kernel 1: feats GEMM + attention-logit epilogue.
// feats stored INTERLEAVED: feats[(n*2 + h)*64 + o]  -> one 512B region per node.
// a_s / a_n stored as float2 per node: a_s[n] = {head0, head1}.
// Block = 128 threads = 2 waves; wave h owns head h, lane = output dim o.
// ---------------------------------------------------------------------------
__global__ __launch_bounds__(128) void feats_kernel(
    const float* __restrict__ X, const float* __restrict__ W,
    const float* __restrict__ attn_self, const float* __restrict__ attn_neigh,
    float* __restrict__ feats, float* __restrict__ a_s, float* __restrict__ a_n)
{
    __shared__ float Xs[ROWS][F_IN];   // 4 KB
    const int tid = threadIdx.x;
    const int n0  = blockIdx.x * ROWS;

    for (int k = tid; k < ROWS * F_IN; k += 128) {
        Xs[k / F_IN][k % F_IN] = X[(size_t)(n0 + k / F_IN) * F_IN + (k % F_IN)];
    }
    __syncthreads();

    const int h = tid >> 6;
    const int o = tid & 63;
    const float* Wh = W + (size_t)h * F_IN * F_OUT;

    float acc[ROWS];
    #pragma unroll
    for (int r = 0; r < ROWS; ++r) acc[r] = 0.f;

    for (int f = 0; f < F_IN; ++f) {
        float wv = Wh[f * F_OUT + o];      // coalesced, L1/L2-resident
        #pragma unroll
        for (int r = 0; r < ROWS; ++r) acc[r] += Xs[r][f] * wv;
    }

    const float asv = attn_self[h * F_OUT + o];
    const float anv = attn_neigh[h * F_OUT + o];
    #pragma unroll
    for (int r = 0; r < ROWS; ++r) {
        const int n = n0 + r;
        const float v = acc[r];
        feats[((size_t)n * 2 + h) * F_OUT + o] = v;   // interleaved [n][h][o]
        float s = v * asv;
        float t = v * anv;
        #pragma unroll
        for (int off = 32; off > 0; off >>= 1) {
            s += __shfl_down(s, off);
            t += __shfl_down(t, off);
        }
        if (o == 0) {
            a_s[n * 2 + h] = s;    // float2-interleaved
            a_n[n * 2 + h] = t;
        }
    }
}

// ---------------------------------------------------------------------------
// Kernel 2 (fused): ONE WAVE PER ROW, 8192 waves = fully resident.
// Scan pipeline: 8 groups x 4KB (4 x f32x4 per lane), double-buffered ->
// 4 nontemporal loads in flight per wave. Ballot compaction (atomic-free)
// into wave-private LDS; softmax via shfl; interleaved-feats gather.
// No __syncthreads anywhere.
// ---------------------------------------------------------------------------
__global__ __launch_bounds__(256) void fused_row_kernel(
    const float* __restrict__ A, const float* __restrict__ feats,
    const float* __restrict__ a_s, const float* __restrict__ a_n,
    const float* __restrict__ biases, float* __restrict__ out)
{
    __shared__ int   jj_s[4][CAP];   // 2 KB
    __shared__ float w0_s[4][CAP];   // 2 KB
    __shared__ float w1_s[4][CAP];   // 2 KB

    const int wave = threadIdx.x >> 6;
    const int lane = threadIdx.x & 63;
    const int row  = blockIdx.x * 4 + wave;

    int*   jj = jj_s[wave];
    float* w0 = w0_s[wave];
    float* w1 = w1_s[wave];

    const unsigned long long lt = (1ULL << lane) - 1ULL;   // lanes-below mask

    // ---- Phase 1: stream + compact A row (4 loads in flight per wave) ----
    const f32x4* Arow = (const f32x4*)(A + (size_t)row * N_NODES);  // 2048 f32x4
    f32x4 buf[2][4];
    #pragma unroll
    for (int q = 0; q < 4; ++q)
        buf[0][q] = __builtin_nontemporal_load(&Arow[q * 64 + lane]);

    int base = 0;                                   // wave-uniform running count
    #pragma unroll
    for (int g = 0; g < 8; ++g) {                   // 8 groups x 4 KB = 32 KB row
        const int cb = g & 1, nb = cb ^ 1;
        if (g < 7) {
            #pragma unroll
            for (int q = 0; q < 4; ++q)
                buf[nb][q] = __builtin_nontemporal_load(
                    &Arow[(g + 1) * 256 + q * 64 + lane]);
        }
        #pragma unroll
        for (int q = 0; q < 4; ++q) {
            const f32x4 v = buf[cb][q];
            const int col0 = (g * 256 + q * 64 + lane) * 4;
            #pragma unroll
            for (int comp = 0; comp < 4; ++comp) {
                const bool nz = v[comp] > 0.5f;
                const unsigned long long m = __ballot(nz);
                if (nz) {
                    const int p = base + __popcll(m & lt);
                    if (p < CAP) jj[p] = col0 + comp;
                }
                base += __popcll(m);                // uniform scalar add
            }
        }
    }
    const int count = min(base, CAP);               // self-loop -> count >= 1

    // ---- Phase 2: logits + softmax (both heads), shfl reductions ----
    const float2 as = ((const float2*)a_s)[row];
    float m0 = -FLT_MAX, m1 = -FLT_MAX;
    for (int k = lane; k < count; k += 64) {
        const float2 an = ((const float2*)a_n)[jj[k]];   // one 8B load per j
        float e0 = as.x + an.x;  e0 = e0 > 0.f ? e0 : LEAKY * e0;
        float e1 = as.y + an.y;  e1 = e1 > 0.f ? e1 : LEAKY * e1;
        w0[k] = e0; w1[k] = e1;
        m0 = fmaxf(m0, e0); m1 = fmaxf(m1, e1);
    }
    #pragma unroll
    for (int off = 32; off > 0; off >>= 1) {
        m0 = fmaxf(m0, __shfl_xor(m0, off));
        m1 = fmaxf(m1, __shfl_xor(m1, off));
    }
    float s0 = 0.f, s1 = 0.f;
    for (int k = lane; k < count; k += 64) {
        const float p0 = __expf(w0[k] - m0); w0[k] = p0; s0 += p0;
        const float p1 = __expf(w1[k] - m1); w1[k] = p1; s1 += p1;
    }
    #pragma unroll
    for (int off = 32; off > 0; off >>= 1) {
        s0 += __shfl_xor(s0, off);
        s1 += __shfl_xor(s1, off);
    }

    // ---- Phase 3: gather from interleaved feats [n][h][o] (512B per j) ----
    float acc0 = 0.f, acc1 = 0.f;
    int k = 0;
    for (; k + 1 < count; k += 2) {                 // unroll x2 for ILP
        const int j0 = jj[k], j1 = jj[k + 1];
        const float* r0 = feats + (size_t)j0 * 128;
        const float* r1 = feats + (size_t)j1 * 128;
        const float p00 = w0[k],     p10 = w1[k];
        const float p01 = w0[k + 1], p11 = w1[k + 1];
        const float f00 = r0[lane], f01 = r0[64 + lane];
        const float f10 = r1[lane], f11 = r1[64 + lane];
        acc0 += p00 * f00; acc1 += p10 * f01;
        acc0 += p01 * f10; acc1 += p11 * f11;
    }
    if (k < count) {
        const int j = jj[k];
        const float* r = feats + (size_t)j * 128;
        acc0 += w0[k] * r[lane];
        acc1 += w1[k] * r[64 + lane];
    }
    const float v = 0.5f * ((acc0 / s0 + biases[lane]) +
                            (acc1 / s1 + biases[F_OUT + lane]));
    out[(size_t)row * F_OUT + lane] = v > 0.f ? v : 0.f;   // mean + relu
}

extern "C" void kernel_launch(void* const* d_in, const int* in_sizes, int n_in,
                              void* d_out, int out_size, void* d_ws, size_t ws_size,
                              hipStream_t stream) {
    const float* X          = (const float*)d_in[0];  // [8192, 128]
    const float* A          = (const float*)d_in[1];  // [8192, 8192]
    const float* W          = (const float*)d_in[2];  // [2, 128, 64]
    const float* biases     = (const float*)d_in[3];  // [2, 64]
    const float* attn_self  = (const float*)d_in[4];  // [2, 64]
    const float* attn_neigh = (const float*)d_in[5];  // [2, 64]
    float* out = (float*)d_out;                       // [8192, 64]

    float* feats = (float*)d_ws;                              // [8192][2][64] = 4 MB
    float* a_s   = feats + (size_t)HEADS * N_NODES * F_OUT;   // float2[8192]
    float* a_n   = a_s + HEADS * N_NODES;                     // float2[8192]

    feats_kernel<<<N_NODES / ROWS, 128, 0, stream>>>(
        X, W, attn_self, attn_neigh, feats, a_s, a_n);
    fused_row_kernel<<<N_NODES / 4, 256, 0, stream>>>(
        A, feats, a_s, a_n, biases, out);
}